// Round 1
// baseline (1127.818 us; speedup 1.0000x reference)
//
#include <hip/hip_runtime.h>

#define B_ROWS 8192
#define DIM_   4096
#define HID_   256
#define NH_    16
#define SEQ_   2048

typedef __attribute__((ext_vector_type(8))) short short8;
typedef __attribute__((ext_vector_type(4))) float float4v;
typedef unsigned short ushort_t;

typedef const void __attribute__((address_space(1)))* as1_cvp;
typedef void __attribute__((address_space(3)))* as3_vp;

__device__ __forceinline__ void gload_lds16(const void* g, void* l) {
  __builtin_amdgcn_global_load_lds((as1_cvp)g, (as3_vp)l, 16, 0, 0);
}

// RNE float -> bf16 (finite inputs only)
__device__ __forceinline__ ushort_t f2bf(float f) {
  union { float f; unsigned u; } a;
  a.f = f;
  unsigned r = a.u + 0x7FFFu + ((a.u >> 16) & 1u);
  return (ushort_t)(r >> 16);
}

// ---------------- coefficient kernel (16 threads) ----------------
// coefs[0..15]=w, coefs[16..31]=cache_coef, coefs[32..47]=b
__global__ void coef_kernel(const float* __restrict__ w_mix, const float* __restrict__ b_mix,
                            const float* __restrict__ decay_values, const int* __restrict__ index,
                            float* __restrict__ coefs) {
  int h = threadIdx.x;
  if (h >= NH_) return;
  int idx = *index;
  float w = w_mix[h * SEQ_ + idx];
  float b = b_mix[h * SEQ_ + idx];
  float d = fminf(fmaxf(decay_values[h], 0.9f), 1.0f);
  d = powf(d, 0.25f);  // 1 / DECAY_CONSTANT, DECAY_CONSTANT = SEQ//512 = 4
  float cc = (h < NH_ / 2) ? (w * d) : d;
  coefs[h] = w;
  coefs[NH_ + h] = cc;
  coefs[2 * NH_ + h] = b;
}

// ---------------- fp32 -> bf16 elementwise (x) ----------------
__global__ void cvt_bf16(const float* __restrict__ in, ushort_t* __restrict__ out) {
  const long i = ((long)blockIdx.x * 256 + threadIdx.x) * 4;
  const float4v v = *(const float4v*)(in + i);
  ushort4 o;
  o.x = f2bf(v.x); o.y = f2bf(v.y); o.z = f2bf(v.z); o.w = f2bf(v.w);
  *(ushort4*)(out + i) = o;
}

// ---------------- transpose-convert W_proj: (16,4096,256) -> (16,256,4096) bf16 ----
__global__ void tr_wproj(const float* __restrict__ in, ushort_t* __restrict__ out) {
  __shared__ float tile[32][33];
  const int h = blockIdx.z;
  const int d0 = blockIdx.x * 32, k0 = blockIdx.y * 32;
  const int tx = threadIdx.x, ty = threadIdx.y;
  const float* src = in + (long)h * DIM_ * HID_;
  #pragma unroll
  for (int j = 0; j < 4; ++j)
    tile[ty + j * 8][tx] = src[(long)(d0 + ty + j * 8) * HID_ + k0 + tx];
  __syncthreads();
  ushort_t* dst = out + (long)h * HID_ * DIM_;
  #pragma unroll
  for (int j = 0; j < 4; ++j)
    dst[(long)(k0 + ty + j * 8) * DIM_ + d0 + tx] = f2bf(tile[tx][ty + j * 8]);
}

// ---------------- transpose-convert W_out: (4096,4096) -> W_out^T bf16 ----------
__global__ void tr_wout(const float* __restrict__ in, ushort_t* __restrict__ out) {
  __shared__ float tile[32][33];
  const int k0 = blockIdx.x * 32, n0 = blockIdx.y * 32;
  const int tx = threadIdx.x, ty = threadIdx.y;
  #pragma unroll
  for (int j = 0; j < 4; ++j)
    tile[ty + j * 8][tx] = in[(long)(k0 + ty + j * 8) * DIM_ + n0 + tx];
  __syncthreads();
  #pragma unroll
  for (int j = 0; j < 4; ++j)
    out[(long)(n0 + ty + j * 8) * DIM_ + k0 + tx] = f2bf(tile[tx][ty + j * 8]);
}

// ---------------- bf16 MFMA GEMM, C = A(MxK) * Bt(NxK)^T, M=8192,N=K=4096 ------
// EPI 0: mixing epilogue -> bf16 hidden ; EPI 1: +b_out -> fp32 out
template <int EPI>
__launch_bounds__(256)
__global__ void gemm_bt(const ushort_t* __restrict__ A, const ushort_t* __restrict__ Bt,
                        const float* __restrict__ b_proj, const float* __restrict__ caches,
                        const float* __restrict__ coefs, const float* __restrict__ b_out,
                        ushort_t* __restrict__ hid_out, float* __restrict__ f_out) {
  __shared__ __attribute__((aligned(16))) ushort_t As[128 * 32];
  __shared__ __attribute__((aligned(16))) ushort_t Bs[128 * 32];
  const int tid = threadIdx.x;
  const int lane = tid & 63;
  const int wave = tid >> 6;
  const int m0 = blockIdx.y * 128;
  const int n0 = blockIdx.x * 128;
  const int wm = (wave >> 1) * 64;  // 2x2 waves, each 64x64
  const int wn = (wave & 1) * 64;
  const int r16 = lane & 15;
  const int quad = lane >> 4;

  float4v acc[4][4];
  #pragma unroll
  for (int i = 0; i < 4; ++i)
    #pragma unroll
    for (int j = 0; j < 4; ++j)
      acc[i][j] = (float4v){0.f, 0.f, 0.f, 0.f};

  const ushort_t* Abase = A + (long)m0 * DIM_;
  const ushort_t* Bbase = Bt + (long)n0 * DIM_;

  for (int kt = 0; kt < DIM_; kt += 32) {
    // stage 128x32 bf16 A-tile and B-tile: 512 16B chunks each, 2 per thread
    #pragma unroll
    for (int i = 0; i < 2; ++i) {
      const int c = tid + i * 256;
      const int row = c >> 2;
      const int kc = c & 3;
      gload_lds16(Abase + (long)row * DIM_ + kt + kc * 8, (void*)(As + c * 8));
      gload_lds16(Bbase + (long)row * DIM_ + kt + kc * 8, (void*)(Bs + c * 8));
    }
    __syncthreads();

    short8 a_frag[4], b_frag[4];
    #pragma unroll
    for (int mi = 0; mi < 4; ++mi)
      a_frag[mi] = *(const short8*)(As + (wm + mi * 16 + r16) * 32 + quad * 8);
    #pragma unroll
    for (int ni = 0; ni < 4; ++ni)
      b_frag[ni] = *(const short8*)(Bs + (wn + ni * 16 + r16) * 32 + quad * 8);
    #pragma unroll
    for (int mi = 0; mi < 4; ++mi)
      #pragma unroll
      for (int ni = 0; ni < 4; ++ni)
        acc[mi][ni] = __builtin_amdgcn_mfma_f32_16x16x32_bf16(a_frag[mi], b_frag[ni], acc[mi][ni], 0, 0, 0);
    __syncthreads();
  }

  // Epilogue. C/D layout: col = lane&15, row = (lane>>4)*4 + reg  [m89/m91]
  if (EPI == 0) {
    #pragma unroll
    for (int ni = 0; ni < 4; ++ni) {
      const int col = n0 + wn + ni * 16 + r16;
      const int h = col >> 8;        // HID_=256
      const int kk = col & 255;
      const float wc = coefs[h];
      const float cc = coefs[16 + h];
      const float bc = coefs[32 + h];
      const float bp = b_proj[h * HID_ + kk];
      #pragma unroll
      for (int mi = 0; mi < 4; ++mi) {
        #pragma unroll
        for (int r = 0; r < 4; ++r) {
          const int row = m0 + wm + mi * 16 + quad * 4 + r;
          float v = wc * (acc[mi][ni][r] + bp)
                  + cc * caches[((long)h * B_ROWS + row) * HID_ + kk] + bc;
          hid_out[(long)row * DIM_ + col] = f2bf(v);
        }
      }
    }
  } else {
    #pragma unroll
    for (int ni = 0; ni < 4; ++ni) {
      const int col = n0 + wn + ni * 16 + r16;
      const float bo = b_out[col];
      #pragma unroll
      for (int mi = 0; mi < 4; ++mi) {
        #pragma unroll
        for (int r = 0; r < 4; ++r) {
          const int row = m0 + wm + mi * 16 + quad * 4 + r;
          f_out[(long)row * DIM_ + col] = acc[mi][ni][r] + bo;
        }
      }
    }
  }
}

extern "C" void kernel_launch(void* const* d_in, const int* in_sizes, int n_in,
                              void* d_out, int out_size, void* d_ws, size_t ws_size,
                              hipStream_t stream) {
  const float* x       = (const float*)d_in[0];
  const int*   index   = (const int*)d_in[1];
  const float* W_proj  = (const float*)d_in[2];
  const float* b_proj  = (const float*)d_in[3];
  const float* W_out   = (const float*)d_in[4];
  const float* b_out   = (const float*)d_in[5];
  const float* w_mix   = (const float*)d_in[6];
  const float* b_mix   = (const float*)d_in[7];
  const float* decay   = (const float*)d_in[8];
  const float* caches  = (const float*)d_in[9];
  float* out = (float*)d_out;

  char* ws = (char*)d_ws;
  // layout: xbf 64MB | Bt1 32MB | Bt2 32MB | hidden 64MB | coefs
  ushort_t* xbf   = (ushort_t*)(ws);
  ushort_t* Bt1   = (ushort_t*)(ws + 67108864L);
  ushort_t* Bt2   = (ushort_t*)(ws + 100663296L);
  ushort_t* hid   = (ushort_t*)(ws + 134217728L);
  float*    coefs = (float*)(ws + 201326592L);

  hipLaunchKernelGGL(coef_kernel, dim3(1), dim3(16), 0, stream,
                     w_mix, b_mix, decay, index, coefs);
  hipLaunchKernelGGL(cvt_bf16, dim3((B_ROWS * (long)DIM_) / 1024), dim3(256), 0, stream, x, xbf);
  hipLaunchKernelGGL(tr_wproj, dim3(DIM_ / 32, HID_ / 32, NH_), dim3(32, 8), 0, stream, W_proj, Bt1);
  hipLaunchKernelGGL(tr_wout, dim3(DIM_ / 32, DIM_ / 32), dim3(32, 8), 0, stream, W_out, Bt2);
  hipLaunchKernelGGL((gemm_bt<0>), dim3(DIM_ / 128, B_ROWS / 128), dim3(256), 0, stream,
                     xbf, Bt1, b_proj, caches, coefs, b_out, hid, out);
  hipLaunchKernelGGL((gemm_bt<1>), dim3(DIM_ / 128, B_ROWS / 128), dim3(256), 0, stream,
                     hid, Bt2, b_proj, caches, coefs, b_out, hid, out);
}

// Round 2
// 1124.095 us; speedup vs baseline: 1.0033x; 1.0033x over previous
//
#include <hip/hip_runtime.h>

#define B_ROWS 8192
#define DIM_   4096
#define HID_   256
#define NH_    16
#define SEQ_   2048
#define BK     64

typedef __attribute__((ext_vector_type(8))) short short8;
typedef __attribute__((ext_vector_type(4))) float float4v;
typedef unsigned short ushort_t;

typedef const void __attribute__((address_space(1)))* as1_cvp;
typedef void __attribute__((address_space(3)))* as3_vp;

__device__ __forceinline__ void gload_lds16(const void* g, void* l) {
  __builtin_amdgcn_global_load_lds((as1_cvp)g, (as3_vp)l, 16, 0, 0);
}

// RNE float -> bf16 (finite inputs only)
__device__ __forceinline__ ushort_t f2bf(float f) {
  union { float f; unsigned u; } a;
  a.f = f;
  unsigned r = a.u + 0x7FFFu + ((a.u >> 16) & 1u);
  return (ushort_t)(r >> 16);
}
__device__ __forceinline__ float bf2f(ushort_t v) {
  union { unsigned u; float f; } a;
  a.u = ((unsigned)v) << 16;
  return a.f;
}

// ---------------- coefficient kernel (16 threads) ----------------
// coefs[0..15]=w, coefs[16..31]=cache_coef, coefs[32..47]=b
__global__ void coef_kernel(const float* __restrict__ w_mix, const float* __restrict__ b_mix,
                            const float* __restrict__ decay_values, const int* __restrict__ index,
                            float* __restrict__ coefs) {
  int h = threadIdx.x;
  if (h >= NH_) return;
  int idx = *index;
  float w = w_mix[h * SEQ_ + idx];
  float b = b_mix[h * SEQ_ + idx];
  float d = fminf(fmaxf(decay_values[h], 0.9f), 1.0f);
  d = powf(d, 0.25f);  // 1/DECAY_CONSTANT, DECAY_CONSTANT = SEQ//512 = 4
  float cc = (h < NH_ / 2) ? (w * d) : d;
  coefs[h] = w;
  coefs[NH_ + h] = cc;
  coefs[2 * NH_ + h] = b;
}

// -------- E = cc[h]*caches + b[h], transposed (H,B,HID)->(B,H*HID), bf16 -------
__global__ void prep_E(const float* __restrict__ caches, const float* __restrict__ coefs,
                       ushort_t* __restrict__ E) {
  const long i = ((long)blockIdx.x * 256 + threadIdx.x) * 4;  // flat over H*B*HID
  const int h = (int)(i >> 21);              // B*HID = 2^21
  const long rem = i & ((1L << 21) - 1);
  const int b = (int)(rem >> 8);             // HID = 2^8
  const int kk = (int)(rem & 255);
  const float cc = coefs[NH_ + h];
  const float bc = coefs[2 * NH_ + h];
  const float4v v = *(const float4v*)(caches + i);
  ushort4 o;
  o.x = f2bf(cc * v.x + bc); o.y = f2bf(cc * v.y + bc);
  o.z = f2bf(cc * v.z + bc); o.w = f2bf(cc * v.w + bc);
  *(ushort4*)(E + (long)b * DIM_ + h * HID_ + kk) = o;
}

// ---------------- fp32 -> bf16 elementwise (x) ----------------
__global__ void cvt_bf16(const float* __restrict__ in, ushort_t* __restrict__ out) {
  const long i = ((long)blockIdx.x * 256 + threadIdx.x) * 4;
  const float4v v = *(const float4v*)(in + i);
  ushort4 o;
  o.x = f2bf(v.x); o.y = f2bf(v.y); o.z = f2bf(v.z); o.w = f2bf(v.w);
  *(ushort4*)(out + i) = o;
}

// ------- transpose-convert W_proj: (16,4096,256) -> (16,256,4096) bf16 --------
__global__ void tr_wproj(const float* __restrict__ in, ushort_t* __restrict__ out) {
  __shared__ float tile[32][33];
  const int h = blockIdx.z;
  const int d0 = blockIdx.x * 32, k0 = blockIdx.y * 32;
  const int tx = threadIdx.x, ty = threadIdx.y;
  const float* src = in + (long)h * DIM_ * HID_;
  #pragma unroll
  for (int j = 0; j < 4; ++j)
    tile[ty + j * 8][tx] = src[(long)(d0 + ty + j * 8) * HID_ + k0 + tx];
  __syncthreads();
  ushort_t* dst = out + (long)h * HID_ * DIM_;
  #pragma unroll
  for (int j = 0; j < 4; ++j)
    dst[(long)(k0 + ty + j * 8) * DIM_ + d0 + tx] = f2bf(tile[tx][ty + j * 8]);
}

// ---------- transpose-convert W_out: (4096,4096) -> W_out^T bf16 --------------
__global__ void tr_wout(const float* __restrict__ in, ushort_t* __restrict__ out) {
  __shared__ float tile[32][33];
  const int k0 = blockIdx.x * 32, n0 = blockIdx.y * 32;
  const int tx = threadIdx.x, ty = threadIdx.y;
  #pragma unroll
  for (int j = 0; j < 4; ++j)
    tile[ty + j * 8][tx] = in[(long)(k0 + ty + j * 8) * DIM_ + n0 + tx];
  __syncthreads();
  #pragma unroll
  for (int j = 0; j < 4; ++j)
    out[(long)(n0 + ty + j * 8) * DIM_ + k0 + tx] = f2bf(tile[tx][ty + j * 8]);
}

// -------- bf16 MFMA GEMM, C = A(MxK) * Bt(NxK)^T, M=8192, N=K=4096 ------------
// BK=64, XOR-swizzled LDS (conflict-free b128 frag reads).
// EPI 0: hidden = w[h]*(acc + b_proj) + E  -> bf16
// EPI 1: out = acc + b_out                 -> fp32
template <int EPI>
__launch_bounds__(256)
__global__ void gemm_bt(const ushort_t* __restrict__ A, const ushort_t* __restrict__ Bt,
                        const float* __restrict__ b_proj, const ushort_t* __restrict__ E,
                        const float* __restrict__ coefs, const float* __restrict__ b_out,
                        ushort_t* __restrict__ hid_out, float* __restrict__ f_out) {
  __shared__ __attribute__((aligned(16))) ushort_t As[128 * BK];
  __shared__ __attribute__((aligned(16))) ushort_t Bs[128 * BK];
  const int tid = threadIdx.x;
  const int lane = tid & 63;
  const int wave = tid >> 6;
  const int m0 = blockIdx.y * 128;
  const int n0 = blockIdx.x * 128;
  const int wm = (wave >> 1) * 64;  // 2x2 waves, each 64x64
  const int wn = (wave & 1) * 64;
  const int r16 = lane & 15;
  const int quad = lane >> 4;

  float4v acc[4][4];
  #pragma unroll
  for (int i = 0; i < 4; ++i)
    #pragma unroll
    for (int j = 0; j < 4; ++j)
      acc[i][j] = (float4v){0.f, 0.f, 0.f, 0.f};

  const ushort_t* Abase = A + (long)m0 * DIM_;
  const ushort_t* Bbase = Bt + (long)n0 * DIM_;

  for (int kt = 0; kt < DIM_; kt += BK) {
    // stage 128xBK A and B tiles; 1024 16B chunks each, 4/thread.
    // XOR swizzle: LDS slot c holds global k-chunk (c&7)^(row&7) of row c>>3
    // -> staging stays lane-contiguous (dest = base + lane*16) and global
    //    reads stay within one fully-coalesced 128B row segment.
    #pragma unroll
    for (int i = 0; i < 4; ++i) {
      const int c = tid + i * 256;
      const int row = c >> 3;
      const int kc = (c & 7) ^ (row & 7);
      gload_lds16(Abase + (long)row * DIM_ + kt + kc * 8, (void*)(As + c * 8));
      gload_lds16(Bbase + (long)row * DIM_ + kt + kc * 8, (void*)(Bs + c * 8));
    }
    __syncthreads();

    #pragma unroll
    for (int ks = 0; ks < BK / 32; ++ks) {
      short8 a_frag[4], b_frag[4];
      // frag (row, k-chunk ks*4+quad) lives at swizzled slot:
      // row&7 == r16&7 (wm, mi*16 are multiples of 8)
      #pragma unroll
      for (int mi = 0; mi < 4; ++mi) {
        const int slot = (ks * 4 + quad) ^ (r16 & 7);
        a_frag[mi] = *(const short8*)(As + (wm + mi * 16 + r16) * BK + slot * 8);
      }
      #pragma unroll
      for (int ni = 0; ni < 4; ++ni) {
        const int slot = (ks * 4 + quad) ^ (r16 & 7);
        b_frag[ni] = *(const short8*)(Bs + (wn + ni * 16 + r16) * BK + slot * 8);
      }
      #pragma unroll
      for (int mi = 0; mi < 4; ++mi)
        #pragma unroll
        for (int ni = 0; ni < 4; ++ni)
          acc[mi][ni] = __builtin_amdgcn_mfma_f32_16x16x32_bf16(a_frag[mi], b_frag[ni], acc[mi][ni], 0, 0, 0);
    }
    __syncthreads();
  }

  // Epilogue. C/D layout: col = lane&15, row = (lane>>4)*4 + reg  [m89/m91]
  if (EPI == 0) {
    #pragma unroll
    for (int ni = 0; ni < 4; ++ni) {
      const int col = n0 + wn + ni * 16 + r16;
      const int h = col >> 8;  // HID_=256
      const float wc = coefs[h];
      const float bp = b_proj[col];  // flat (H,HID) == col
      #pragma unroll
      for (int mi = 0; mi < 4; ++mi) {
        #pragma unroll
        for (int r = 0; r < 4; ++r) {
          const long row = m0 + wm + mi * 16 + quad * 4 + r;
          const float e = bf2f(E[row * DIM_ + col]);
          hid_out[row * DIM_ + col] = f2bf(wc * (acc[mi][ni][r] + bp) + e);
        }
      }
    }
  } else {
    #pragma unroll
    for (int ni = 0; ni < 4; ++ni) {
      const int col = n0 + wn + ni * 16 + r16;
      const float bo = b_out[col];
      #pragma unroll
      for (int mi = 0; mi < 4; ++mi) {
        #pragma unroll
        for (int r = 0; r < 4; ++r) {
          const long row = m0 + wm + mi * 16 + quad * 4 + r;
          f_out[row * DIM_ + col] = acc[mi][ni][r] + bo;
        }
      }
    }
  }
}

extern "C" void kernel_launch(void* const* d_in, const int* in_sizes, int n_in,
                              void* d_out, int out_size, void* d_ws, size_t ws_size,
                              hipStream_t stream) {
  const float* x       = (const float*)d_in[0];
  const int*   index   = (const int*)d_in[1];
  const float* W_proj  = (const float*)d_in[2];
  const float* b_proj  = (const float*)d_in[3];
  const float* W_out   = (const float*)d_in[4];
  const float* b_out   = (const float*)d_in[5];
  const float* w_mix   = (const float*)d_in[6];
  const float* b_mix   = (const float*)d_in[7];
  const float* decay   = (const float*)d_in[8];
  const float* caches  = (const float*)d_in[9];
  float* out = (float*)d_out;

  char* ws = (char*)d_ws;
  // layout: xbf 64MB | Bt 32MB (Wproj^T, then Wout^T) | hid 64MB | E 64MB | coefs
  ushort_t* xbf   = (ushort_t*)(ws);
  ushort_t* Bt    = (ushort_t*)(ws + 67108864L);
  ushort_t* hid   = (ushort_t*)(ws + 100663296L);
  ushort_t* Ebuf  = (ushort_t*)(ws + 167772160L);
  float*    coefs = (float*)(ws + 234881024L);

  hipLaunchKernelGGL(coef_kernel, dim3(1), dim3(16), 0, stream,
                     w_mix, b_mix, decay, index, coefs);
  hipLaunchKernelGGL(prep_E, dim3((NH_ * (long)B_ROWS * HID_) / 1024), dim3(256), 0, stream,
                     caches, coefs, Ebuf);
  hipLaunchKernelGGL(cvt_bf16, dim3((B_ROWS * (long)DIM_) / 1024), dim3(256), 0, stream, x, xbf);
  hipLaunchKernelGGL(tr_wproj, dim3(DIM_ / 32, HID_ / 32, NH_), dim3(32, 8), 0, stream, W_proj, Bt);
  hipLaunchKernelGGL((gemm_bt<0>), dim3(DIM_ / 128, B_ROWS / 128), dim3(256), 0, stream,
                     xbf, Bt, b_proj, Ebuf, coefs, b_out, hid, out);
  hipLaunchKernelGGL(tr_wout, dim3(DIM_ / 32, DIM_ / 32), dim3(32, 8), 0, stream, W_out, Bt);
  hipLaunchKernelGGL((gemm_bt<1>), dim3(DIM_ / 128, B_ROWS / 128), dim3(256), 0, stream,
                     hid, Bt, b_proj, Ebuf, coefs, b_out, hid, out);
}

// Round 3
// 1079.941 us; speedup vs baseline: 1.0443x; 1.0409x over previous
//
#include <hip/hip_runtime.h>

#define B_ROWS 8192
#define DIM_   4096
#define HID_   256
#define NH_    16
#define SEQ_   2048
#define BK     64

typedef __attribute__((ext_vector_type(8))) short short8;
typedef __attribute__((ext_vector_type(4))) float float4v;
typedef unsigned short ushort_t;

typedef const void __attribute__((address_space(1)))* as1_cvp;
typedef void __attribute__((address_space(3)))* as3_vp;

__device__ __forceinline__ void gload_lds16(const void* g, void* l) {
  __builtin_amdgcn_global_load_lds((as1_cvp)g, (as3_vp)l, 16, 0, 0);
}

// RNE float -> bf16 (finite inputs only)
__device__ __forceinline__ ushort_t f2bf(float f) {
  union { float f; unsigned u; } a;
  a.f = f;
  unsigned r = a.u + 0x7FFFu + ((a.u >> 16) & 1u);
  return (ushort_t)(r >> 16);
}
__device__ __forceinline__ float bf2f(ushort_t v) {
  union { unsigned u; float f; } a;
  a.u = ((unsigned)v) << 16;
  return a.f;
}

// ---------------- merged prep kernel --------------------------------------
// blocks [0,8192):      cvt x (fp32->bf16), 4096 elems/block
// blocks [8192,16384):  E = cc[h]*caches + b[h], (H,B,HID)->(B,H*HID) bf16
// blocks [16384,20480): tr_wproj (16,4096,256)->(16,256,4096) bf16, 64x64 tiles
__global__ __launch_bounds__(256)
void uber_prep(const float* __restrict__ x, ushort_t* __restrict__ xbf,
               const float* __restrict__ caches, const float* __restrict__ w_mix,
               const float* __restrict__ b_mix, const float* __restrict__ decay,
               const int* __restrict__ index, ushort_t* __restrict__ E,
               const float* __restrict__ W_proj, ushort_t* __restrict__ Bt) {
  __shared__ float tile[64][65];
  const int bid = blockIdx.x;
  const int tid = threadIdx.x;
  if (bid < 8192) {
    const long base = (long)bid * 4096 + tid * 4;
    #pragma unroll
    for (int j = 0; j < 4; ++j) {
      const long i = base + j * 1024;
      const float4v v = *(const float4v*)(x + i);
      ushort4 o;
      o.x = f2bf(v.x); o.y = f2bf(v.y); o.z = f2bf(v.z); o.w = f2bf(v.w);
      *(ushort4*)(xbf + i) = o;
    }
  } else if (bid < 16384) {
    const int b2 = bid - 8192;
    const int h = b2 >> 9;  // 512 blocks per h (2^21 elems / 4096)
    const int idx = *index;
    const float w = w_mix[h * SEQ_ + idx];
    const float bc = b_mix[h * SEQ_ + idx];
    float d = fminf(fmaxf(decay[h], 0.9f), 1.0f);
    d = powf(d, 0.25f);  // 1/DECAY_CONSTANT, DECAY_CONSTANT = SEQ//512 = 4
    const float cc = (h < NH_ / 2) ? (w * d) : d;
    const long base = (long)b2 * 4096 + tid * 4;
    #pragma unroll
    for (int j = 0; j < 4; ++j) {
      const long i = base + j * 1024;          // flat over (H,B,HID)
      const long rem = i & ((1L << 21) - 1);
      const int bb = (int)(rem >> 8);
      const int kk = (int)(rem & 255);
      const float4v v = *(const float4v*)(caches + i);
      ushort4 o;
      o.x = f2bf(cc * v.x + bc); o.y = f2bf(cc * v.y + bc);
      o.z = f2bf(cc * v.z + bc); o.w = f2bf(cc * v.w + bc);
      *(ushort4*)(E + (long)bb * DIM_ + h * HID_ + kk) = o;
    }
  } else {
    const int b2 = bid - 16384;
    const int h = b2 >> 8;
    const int t = b2 & 255;
    const int M0 = (t & 63) * 64;   // over DIM
    const int N0 = (t >> 6) * 64;   // over HID
    const float* src = W_proj + (long)h * DIM_ * HID_;
    #pragma unroll
    for (int j = 0; j < 4; ++j) {
      const int row = (tid >> 4) + j * 16;
      const int c = (tid & 15) * 4;
      const float4v v = *(const float4v*)(src + (long)(M0 + row) * HID_ + N0 + c);
      tile[row][c] = v.x; tile[row][c + 1] = v.y;
      tile[row][c + 2] = v.z; tile[row][c + 3] = v.w;
    }
    __syncthreads();
    ushort_t* dst = Bt + (long)h * HID_ * DIM_;
    #pragma unroll
    for (int j = 0; j < 4; ++j) {
      const int orow = (tid >> 4) + j * 16;   // over HID
      const int oc = (tid & 15) * 4;          // over DIM
      ushort4 o;
      o.x = f2bf(tile[oc][orow]);     o.y = f2bf(tile[oc + 1][orow]);
      o.z = f2bf(tile[oc + 2][orow]); o.w = f2bf(tile[oc + 3][orow]);
      *(ushort4*)(dst + (long)(N0 + orow) * DIM_ + M0 + oc) = o;
    }
  }
}

// ---------- transpose-convert W_out: (4096,4096) -> W_out^T bf16, 64x64 ------
__global__ __launch_bounds__(256)
void tr_wout(const float* __restrict__ in, ushort_t* __restrict__ out) {
  __shared__ float tile[64][65];
  const int tid = threadIdx.x;
  const int t = blockIdx.x;
  const int M0 = (t & 63) * 64;
  const int N0 = (t >> 6) * 64;
  #pragma unroll
  for (int j = 0; j < 4; ++j) {
    const int row = (tid >> 4) + j * 16;
    const int c = (tid & 15) * 4;
    const float4v v = *(const float4v*)(in + (long)(M0 + row) * DIM_ + N0 + c);
    tile[row][c] = v.x; tile[row][c + 1] = v.y;
    tile[row][c + 2] = v.z; tile[row][c + 3] = v.w;
  }
  __syncthreads();
  #pragma unroll
  for (int j = 0; j < 4; ++j) {
    const int orow = (tid >> 4) + j * 16;
    const int oc = (tid & 15) * 4;
    ushort4 o;
    o.x = f2bf(tile[oc][orow]);     o.y = f2bf(tile[oc + 1][orow]);
    o.z = f2bf(tile[oc + 2][orow]); o.w = f2bf(tile[oc + 3][orow]);
    *(ushort4*)(out + (long)(N0 + orow) * DIM_ + M0 + oc) = o;
  }
}

// -------- bf16 MFMA GEMM, C = A(MxK) * Bt(NxK)^T, M=8192, N=K=4096 ------------
// BK=64, XOR-swizzled LDS (zero bank conflicts, verified R2).
// LDS-retiled coalesced epilogues:
//   EPI 0: hid = w[h]*(acc + b_proj) + E   -> bf16 (16B/lane E-read + store)
//   EPI 1: out = acc + b_out               -> fp32 (float4 stores)
template <int EPI>
__launch_bounds__(256)
__global__ void gemm_bt(const ushort_t* __restrict__ A, const ushort_t* __restrict__ Bt,
                        const float* __restrict__ b_proj, const ushort_t* __restrict__ E,
                        const float* __restrict__ w_mix, const int* __restrict__ index,
                        const float* __restrict__ b_out,
                        ushort_t* __restrict__ hid_out, float* __restrict__ f_out) {
  __shared__ __attribute__((aligned(16))) ushort_t lds[2 * 128 * BK];  // 32 KB
  ushort_t* As = lds;
  ushort_t* Bs = lds + 128 * BK;
  const int tid = threadIdx.x;
  const int lane = tid & 63;
  const int wave = tid >> 6;
  const int m0 = blockIdx.y * 128;
  const int n0 = blockIdx.x * 128;
  const int wm = (wave >> 1) * 64;  // 2x2 waves, each 64x64
  const int wn = (wave & 1) * 64;
  const int r16 = lane & 15;
  const int quad = lane >> 4;

  float4v acc[4][4];
  #pragma unroll
  for (int i = 0; i < 4; ++i)
    #pragma unroll
    for (int j = 0; j < 4; ++j)
      acc[i][j] = (float4v){0.f, 0.f, 0.f, 0.f};

  const ushort_t* Abase = A + (long)m0 * DIM_;
  const ushort_t* Bbase = Bt + (long)n0 * DIM_;

  for (int kt = 0; kt < DIM_; kt += BK) {
    // stage 128xBK A and B tiles; XOR swizzle keeps frag reads conflict-free
    // while staging stays lane-contiguous (dest = wave base + lane*16).
    #pragma unroll
    for (int i = 0; i < 4; ++i) {
      const int c = tid + i * 256;
      const int row = c >> 3;
      const int kc = (c & 7) ^ (row & 7);
      gload_lds16(Abase + (long)row * DIM_ + kt + kc * 8, (void*)(As + c * 8));
      gload_lds16(Bbase + (long)row * DIM_ + kt + kc * 8, (void*)(Bs + c * 8));
    }
    __syncthreads();

    #pragma unroll
    for (int ks = 0; ks < BK / 32; ++ks) {
      short8 a_frag[4], b_frag[4];
      const int slot = (ks * 4 + quad) ^ (r16 & 7);
      #pragma unroll
      for (int mi = 0; mi < 4; ++mi)
        a_frag[mi] = *(const short8*)(As + (wm + mi * 16 + r16) * BK + slot * 8);
      #pragma unroll
      for (int ni = 0; ni < 4; ++ni)
        b_frag[ni] = *(const short8*)(Bs + (wn + ni * 16 + r16) * BK + slot * 8);
      #pragma unroll
      for (int mi = 0; mi < 4; ++mi)
        #pragma unroll
        for (int ni = 0; ni < 4; ++ni)
          acc[mi][ni] = __builtin_amdgcn_mfma_f32_16x16x32_bf16(a_frag[mi], b_frag[ni], acc[mi][ni], 0, 0, 0);
    }
    __syncthreads();
  }

  // Epilogue. C/D layout: col = lane&15, row = (lane>>4)*4 + reg  [m89/m91]
  if (EPI == 0) {
    // stage w[h]*(acc+bp) as bf16 into 128x128 LDS tile (aliases As/Bs)
    ushort_t* Cs = lds;
    const int idx0 = *index;
    #pragma unroll
    for (int ni = 0; ni < 4; ++ni) {
      const int col = wn + ni * 16 + r16;
      const int gcol = n0 + col;
      const float wc = w_mix[(gcol >> 8) * SEQ_ + idx0];
      const float bp = b_proj[gcol];
      #pragma unroll
      for (int mi = 0; mi < 4; ++mi)
        #pragma unroll
        for (int r = 0; r < 4; ++r) {
          const int lrow = wm + mi * 16 + quad * 4 + r;
          Cs[lrow * 128 + col] = f2bf(wc * (acc[mi][ni][r] + bp));
        }
    }
    __syncthreads();
    // coalesced writeout: += E, 16B/lane
    #pragma unroll
    for (int j = 0; j < 8; ++j) {
      const int idx = tid + j * 256;
      const int row = idx >> 4;
      const int seg = idx & 15;
      const short8 c8 = *(const short8*)(Cs + row * 128 + seg * 8);
      const short8 e8 = *(const short8*)(E + (long)(m0 + row) * DIM_ + n0 + seg * 8);
      short8 o;
      #pragma unroll
      for (int k = 0; k < 8; ++k)
        o[k] = (short)f2bf(bf2f((ushort_t)c8[k]) + bf2f((ushort_t)e8[k]));
      *(short8*)(hid_out + (long)(m0 + row) * DIM_ + n0 + seg * 8) = o;
    }
  } else {
    float* Cf = (float*)lds;  // 64x128 fp32 = 32 KB, two half-tiles
    #pragma unroll
    for (int half = 0; half < 2; ++half) {
      __syncthreads();
      if ((wm >> 6) == half) {
        #pragma unroll
        for (int ni = 0; ni < 4; ++ni) {
          const int col = wn + ni * 16 + r16;
          #pragma unroll
          for (int mi = 0; mi < 4; ++mi)
            #pragma unroll
            for (int r = 0; r < 4; ++r)
              Cf[(mi * 16 + quad * 4 + r) * 128 + col] = acc[mi][ni][r];
        }
      }
      __syncthreads();
      #pragma unroll
      for (int j = 0; j < 8; ++j) {
        const int idx = tid + j * 256;
        const int row = idx >> 5;
        const int seg = idx & 31;
        float4v v = *(const float4v*)(Cf + row * 128 + seg * 4);
        const float4v bo = *(const float4v*)(b_out + n0 + seg * 4);
        v.x += bo.x; v.y += bo.y; v.z += bo.z; v.w += bo.w;
        *(float4v*)(f_out + (long)(m0 + half * 64 + row) * DIM_ + n0 + seg * 4) = v;
      }
    }
  }
}

extern "C" void kernel_launch(void* const* d_in, const int* in_sizes, int n_in,
                              void* d_out, int out_size, void* d_ws, size_t ws_size,
                              hipStream_t stream) {
  const float* x       = (const float*)d_in[0];
  const int*   index   = (const int*)d_in[1];
  const float* W_proj  = (const float*)d_in[2];
  const float* b_proj  = (const float*)d_in[3];
  const float* W_out   = (const float*)d_in[4];
  const float* b_out   = (const float*)d_in[5];
  const float* w_mix   = (const float*)d_in[6];
  const float* b_mix   = (const float*)d_in[7];
  const float* decay   = (const float*)d_in[8];
  const float* caches  = (const float*)d_in[9];
  float* out = (float*)d_out;

  char* ws = (char*)d_ws;
  // layout: xbf 64MB | Bt 32MB (Wproj^T, then Wout^T) | hid 64MB | E 64MB  = 224MB
  ushort_t* xbf  = (ushort_t*)(ws);
  ushort_t* Bt   = (ushort_t*)(ws + 67108864L);
  ushort_t* hid  = (ushort_t*)(ws + 100663296L);
  ushort_t* Ebuf = (ushort_t*)(ws + 167772160L);

  hipLaunchKernelGGL(uber_prep, dim3(20480), dim3(256), 0, stream,
                     x, xbf, caches, w_mix, b_mix, decay, index, Ebuf, W_proj, Bt);
  hipLaunchKernelGGL((gemm_bt<0>), dim3(DIM_ / 128, B_ROWS / 128), dim3(256), 0, stream,
                     xbf, Bt, b_proj, Ebuf, w_mix, index, b_out, hid, out);
  hipLaunchKernelGGL(tr_wout, dim3(4096), dim3(256), 0, stream, W_out, Bt);
  hipLaunchKernelGGL((gemm_bt<1>), dim3(DIM_ / 128, B_ROWS / 128), dim3(256), 0, stream,
                     hid, Bt, b_proj, Ebuf, w_mix, index, b_out, hid, out);
}